// Round 11
// baseline (195.557 us; speedup 1.0000x reference)
//
#include <hip/hip_runtime.h>
#include <math.h>

#define NPTS    131072
#define PPB     32            // points per block (4 waves x 8 points, 1 B-tile/wave)
#define THREADS 256
#define NBLK    (NPTS / PPB)  // 4096
#define HOFF    (7 * 16384)   // head-weight offset in wsW (bf16 elems)
#define HSZ     (32 * 128)    // head block: 32 rows (6 used), 128 k

typedef __attribute__((ext_vector_type(8)))  short short8;
typedef __attribute__((ext_vector_type(16))) float f32x16;
typedef __attribute__((ext_vector_type(2)))  short s16x2;
typedef __attribute__((ext_vector_type(2)))  __bf16 bf16x2v;

union b8cv { short8 v; unsigned u[4]; };

__device__ __forceinline__ unsigned short f2bf(float f) {
  unsigned u = __float_as_uint(f);
  unsigned r = (u + 0x7fffu + ((u >> 16) & 1u)) >> 16;
  return (unsigned short)r;
}
// Native bf16 pack: gfx950 lowers fptrunc f32->bf16 to v_cvt_pk_bf16_f32
// (compiler-native casts get correct VALU->DPP hazard handling).
__device__ __forceinline__ unsigned pk2(float lo, float hi) {
  bf16x2v t;
  t[0] = (__bf16)lo;
  t[1] = (__bf16)hi;
  unsigned u; __builtin_memcpy(&u, &t, 4); return u;
}
__device__ __forceinline__ void gld16(const unsigned short* g, unsigned short* l) {
  __builtin_amdgcn_global_load_lds(
      (const __attribute__((address_space(1))) unsigned int*)(g),
      (__attribute__((address_space(3))) unsigned int*)(l), 16, 0, 0);
}
// rematerializable zero accumulator (not kept live across the kernel)
__device__ __forceinline__ f32x16 zf() {
  f32x16 z;
  #pragma unroll
  for (int e = 0; e < 16; ++e) z[e] = 0.0f;
  return z;
}
// broadcast the value-lane (lane & ~3) element of each 4-lane group: DPP quad_perm[0,0,0,0]
__device__ __forceinline__ float qbcast0(float v) {
  return __int_as_float(
      __builtin_amdgcn_mov_dpp(__float_as_int(v), 0x000, 0xf, 0xf, true));
}
// packed-bf16 ReLU with quad value-lane masking
__device__ __forceinline__ unsigned relu_pk(unsigned p) {
  unsigned vs = (unsigned)__builtin_amdgcn_mov_dpp((int)p, 0x000, 0xf, 0xf, true);
  s16x2 m2; __builtin_memcpy(&m2, &vs, 4);
  m2 = m2 >> 15;                          // 0xFFFF per negative half
  unsigned m; __builtin_memcpy(&m, &m2, 4);
  unsigned r;
  asm("v_bfi_b32 %0, %1, 0, %2" : "=v"(r) : "v"(m), "v"(p));
  return r;
}
__device__ __forceinline__ void cross3(const float a[3], const float b[3], float o[3]) {
  o[0] = a[1]*b[2] - a[2]*b[1];
  o[1] = a[2]*b[0] - a[0]*b[2];
  o[2] = a[0]*b[1] - a[1]*b[0];
}
__device__ __forceinline__ float dot3(const float a[3], const float b[3]) {
  return a[0]*b[0] + a[1]*b[1] + a[2]*b[2];
}

// ---- weights -> bf16 workspace: 7x[128c][128k] identity + heads 32x128 ----
// Biases stuffed into layer-0's dead k>=64 space (see r3 derivation):
//   flat j = l*128 + mt*32 + rD -> wsW elem (j>>6)*128 + 64 + (j&63).
__global__ void convert_weights(const float* __restrict__ W_in,
                                const float* __restrict__ b_in,
                                const float* __restrict__ Ws,
                                const float* __restrict__ bs,
                                const float* __restrict__ Ww,
                                const float* __restrict__ Wv,
                                unsigned short* __restrict__ wsW) {
  int idx = blockIdx.x * 256 + threadIdx.x;
  if (idx >= HOFF + HSZ) return;
  float v;
  if (idx < HOFF) {
    int l = idx >> 14, r = idx & 16383, c = r >> 7, k = r & 127;
    if (l == 0) {
      if (k < 39) {
        v = W_in[c * 39 + k];
      } else if (k >= 64 && c < 14) {
        int j  = c * 64 + (k - 64);          // 0..895
        int lb = j >> 7, rr = j & 127;
        int mt = rr >> 5, rd = rr & 31;
        int e2 = rd & 3, hh = (rd >> 2) & 1, q = rd >> 3;
        int src = 32*mt + 16*(q>>1) + 8*hh + 4*(q&1) + e2;
        v = (lb == 0) ? b_in[src] : bs[(lb - 1) * 128 + src];
      } else {
        v = 0.0f;
      }
    } else {
      v = Ws[(l - 1) * 16384 + c * 128 + k];
    }
  } else {
    int r = idx - HOFF, o = r >> 7, k = r & 127;
    v = (o < 3) ? Ww[o * 128 + k] : (o < 6) ? Wv[(o - 3) * 128 + k] : 0.0f;
  }
  wsW[idx] = f2bf(v);
}

// DMA a 64-row half-layer (16 KB) into an LDS slot, XOR-chunk-swizzled:
// slot row R, chunk-pos chs holds global chunk chs^(R&15).
__device__ __forceinline__ void dma_half(const unsigned short* __restrict__ g,
                                         unsigned short* lds, int tid) {
  #pragma unroll
  for (int i = 0; i < 4; ++i) {
    int flat = i * 256 + tid;
    int R = flat >> 4, chs = flat & 15, ch = chs ^ (R & 15);
    gld16(g + R * 128 + ch * 8, lds + flat * 8);
  }
}

// bias-MFMA A-frag: elem0 = bf16 bias for A-row c32
__device__ __forceinline__ short8 bias_af(const unsigned short* __restrict__ bb,
                                          int off, int c32) {
  b8cv cv;
  cv.u[0] = (unsigned)bb[off + c32];
  cv.u[1] = 0; cv.u[2] = 0; cv.u[3] = 0;
  return cv.v;
}

// activation + pack two m-tiles' results: acc[2] (64 units) -> dst[0..3]
template <bool LEAKY>
__device__ __forceinline__ void act_pack(const f32x16 (&acc)[2], short8* dst) {
  #pragma unroll
  for (int mt = 0; mt < 2; ++mt)
    #pragma unroll
    for (int qh = 0; qh < 2; ++qh) {
      b8cv cv;
      #pragma unroll
      for (int qs = 0; qs < 2; ++qs) {
        int q = 2*qh + qs;
        if (LEAKY) {
          float pr[4];
          #pragma unroll
          for (int e2 = 0; e2 < 4; ++e2) {
            float post = acc[mt][4*q + e2];
            float vraw = qbcast0(post);
            pr[e2] = vraw > 0.0f ? post : post * 0.01f;
          }
          cv.u[2*qs]     = pk2(pr[0], pr[1]);
          cv.u[2*qs + 1] = pk2(pr[2], pr[3]);
        } else {
          cv.u[2*qs]     = relu_pk(pk2(acc[mt][4*q+0], acc[mt][4*q+1]));
          cv.u[2*qs + 1] = relu_pk(pk2(acc[mt][4*q+2], acc[mt][4*q+3]));
        }
      }
      dst[2*mt + qh] = cv.v;
    }
}

// One MLP layer, ONE B-tile (8 points/wave), half-slot staging, 2 barriers.
// Small footprint (~pg32+acc32+tmp16) -> launch_bounds(256,3) fits 3+
// waves/SIMD with 32 KB LDS (3+ blocks/CU): the occupancy covers the
// mid/end barrier drains that pinned the 2-wave structure.
// Bias via rank-1 MFMA as the C-operand of the first chain MFMA (r6-verified).
template <int NKS, bool LEAKY, bool HASNEXT>
__device__ __forceinline__ void mlp_layer(short8 (&pg)[8],
                                          const unsigned short* s0s,
                                          const unsigned short* s1s,
                                          unsigned short* s0w, unsigned short* s1w,
                                          const int (&aoff)[8],
                                          const unsigned short* __restrict__ bb,
                                          const short8 bind,
                                          const unsigned short* __restrict__ Wthis,
                                          const unsigned short* __restrict__ Wnext,
                                          int tid, int c32) {
  dma_half(Wthis + 64 * 128, s1w, tid);   // upper half (units 64-127) into s1

  short8 t[4];                            // phase-1 results (units 0-63)

  // ---- phase 1: units 0-63 (m-tiles 0,1) from s0 ----
  {
    f32x16 a[2];
    __builtin_amdgcn_s_setprio(1);
    #pragma unroll
    for (int m = 0; m < 2; ++m) {
      f32x16 bias = __builtin_amdgcn_mfma_f32_32x32x16_bf16(
          bias_af(bb, 64 + 32*m, c32), bind, zf(), 0, 0, 0);
      short8 af0 = *(const short8*)(s0s + m * 4096 + aoff[0]);
      a[m] = __builtin_amdgcn_mfma_f32_32x32x16_bf16(af0, pg[0], bias, 0, 0, 0);
    }
    #pragma unroll
    for (int ks = 1; ks < NKS; ++ks) {
      #pragma unroll
      for (int m = 0; m < 2; ++m) {
        short8 af = *(const short8*)(s0s + m * 4096 + aoff[ks]);
        a[m] = __builtin_amdgcn_mfma_f32_32x32x16_bf16(af, pg[ks], a[m], 0, 0, 0);
      }
    }
    __builtin_amdgcn_s_setprio(0);
    act_pack<LEAKY>(a, t);
  }

  __syncthreads();                        // s0 reads done; s1 DMA drained
  if (HASNEXT) dma_half(Wnext, s0w, tid); // next layer's units 0-63

  // ---- phase 2: units 64-127 (m-tiles 0,1 of s1) ----
  {
    f32x16 a[2];
    __builtin_amdgcn_s_setprio(1);
    #pragma unroll
    for (int m = 0; m < 2; ++m) {
      f32x16 bias = __builtin_amdgcn_mfma_f32_32x32x16_bf16(
          bias_af(bb, 192 + 32*m, c32), bind, zf(), 0, 0, 0);
      short8 af0 = *(const short8*)(s1s + m * 4096 + aoff[0]);
      a[m] = __builtin_amdgcn_mfma_f32_32x32x16_bf16(af0, pg[0], bias, 0, 0, 0);
    }
    #pragma unroll
    for (int ks = 1; ks < NKS; ++ks) {
      #pragma unroll
      for (int m = 0; m < 2; ++m) {
        short8 af = *(const short8*)(s1s + m * 4096 + aoff[ks]);
        a[m] = __builtin_amdgcn_mfma_f32_32x32x16_bf16(af, pg[ks], a[m], 0, 0, 0);
      }
    }
    __builtin_amdgcn_s_setprio(0);
    // all reads of old pg done -> write phase-2 results directly
    act_pack<LEAKY>(a, &pg[4]);
  }

  #pragma unroll
  for (int i = 0; i < 4; ++i) pg[i] = t[i];
  __syncthreads();     // s1 reads done; s0 DMA drained (also guards sH alias)
}

// ---- posenc with compile-time slot metadata (bit-identical formulas) ----
struct SK { int cls, a, t, jf; };   // cls: 0=zero, 1=pos(a=c), 2=enc
__device__ __forceinline__ constexpr SK slotk(int c) {
  return (c < 3)   ? SK{1, c, 0, 0}
       : (c >= 39) ? SK{0, 0, 0, 0}
       : SK{2, (c-3)/12, ((c-3)%12)/6, ((c-3)%12)%6};
}
__device__ __forceinline__ constexpr float e2sf(int jf) {   // e2 * 0.49974652f
  return (float)(1 << jf) * 0.125f * 0.49974652f;
}
__device__ __forceinline__ float eval_slot(SK k, const float (&X)[3],
                                           float sv, float cvv,
                                           const float (&wjv)[6],
                                           const float (&mjw)[6],
                                           float f_d0, const float (&fea)[3]) {
  if (k.cls == 0) return 0.0f;
  if (k.cls == 1) return X[k.a] * f_d0 + fea[k.a];
  float pv = (k.t ? cvv : sv) * wjv[k.jf];     // value row: (t==0?sin:cos)*wj
  float pt = (k.t ? -sv : cvv) * mjw[k.jf];    // tangent:  (t==0?cos:-sin)*mj*wj
  return pv * f_d0 + pt * fea[k.a];
}

__device__ __forceinline__ void posenc_pack(const float (&X)[3], int h,
                                            const float (&wjv)[6],
                                            const float (&mjw)[6],
                                            float f_d0, const float (&fea)[3],
                                            short8* pg) {
  const bool hI = (h != 0);
  #pragma unroll
  for (int j = 4; j < 8; ++j) pg[j] = (short8)0;
  #pragma unroll
  for (int j = 0; j < 4; ++j) {
    b8cv cv;
    #pragma unroll
    for (int ii = 0; ii < 4; ++ii) {
      int i = 4*j + ii;
      int mt = i >> 3, rr = i & 7, q = rr >> 1, s = rr & 1;
      int u0 = 32*mt + 16*(q>>1) + 4*(q&1) + 2*s;    // h-part handled below
      float vp[2];
      #pragma unroll
      for (int ci = 0; ci < 2; ++ci) {
        const SK k0 = slotk(u0 + ci);          // h = 0 variant
        const SK k1 = slotk(u0 + ci + 8);      // h = 1 variant
        float rev0 = (k0.cls == 2) ? X[k0.a] * e2sf(k0.jf) : 0.0f;
        float rev1 = (k1.cls == 2) ? X[k1.a] * e2sf(k1.jf) : 0.0f;
        float rev  = hI ? rev1 : rev0;
        float fr   = rev - floorf(rev);
        float sv   = __builtin_amdgcn_sinf(fr);
        float cvv  = __builtin_amdgcn_cosf(fr);
        float v0 = eval_slot(k0, X, sv, cvv, wjv, mjw, f_d0, fea);
        float v1 = eval_slot(k1, X, sv, cvv, wjv, mjw, f_d0, fea);
        vp[ci] = hI ? v1 : v0;
      }
      cv.u[ii] = pk2(vp[0], vp[1]);
    }
    pg[j] = cv.v;
  }
}

__global__ __launch_bounds__(THREADS, 3)
void nerfies_mfma(const float* __restrict__ x,
                  const float* __restrict__ bw,
                  const float* __restrict__ bv,
                  const unsigned short* __restrict__ wsW,
                  const int* __restrict__ iterp,
                  float* __restrict__ out)
{
  __shared__ __align__(16) unsigned short sWl[2][64 * 128];  // 2x16 KB half-slots
  float* sH = (float*)sWl[1];                                // heads alias slot 1

  const int tid  = threadIdx.x;
  const int lane = tid & 63;
  const int wv   = tid >> 6;
  const int c32  = lane & 31;
  const int h    = lane >> 5;
  const int p0   = blockIdx.x * PPB;
  // sigma: swap bits 2<->3 (A-row permutation making next-layer B = identity)
  const int sig  = (c32 & 0x13) | ((c32 & 4) << 1) | ((c32 & 8) >> 1);

  // prologue: stage layer-0 units 0-63 into slot 0 (covered by posenc below)
  dma_half(wsW, sWl[0], tid);

  // per-lane A-frag addressing, invariant across ALL layers/phases
  int aoff[8];
  #pragma unroll
  for (int ks = 0; ks < 8; ++ks) aoff[ks] = ((2*ks + h) ^ (sig & 15)) << 3;
  const unsigned short* s0s = sWl[0] + sig * 128;
  const unsigned short* s1s = sWl[1] + sig * 128;

  // bias-MFMA B-frag: 0.5 at k in {0,8} (elem0 of both halves), value cols only
  short8 bind;
  {
    b8cv cv;
    cv.u[0] = ((c32 & 3) == 0) ? 0x3F00u : 0u;
    cv.u[1] = 0; cv.u[2] = 0; cv.u[3] = 0;
    bind = cv.v;
  }

  // lane's act row: point = wv*8 + (c32>>2), tangent d = c32&3
  const int d  = c32 & 3;
  const int gp = p0 + wv * 8 + (c32 >> 2);
  float X[3] = { x[gp * 3 + 0], x[gp * 3 + 1], x[gp * 3 + 2] };

  int iraw = iterp[0];
  float it = (iraw > 0 && iraw < 100000000) ? (float)iraw : ((const float*)iterp)[0];
  const float aM = 6.0f * it / 3000.0f;

  // hoisted posenc constants: anneal weights (6 jf) + row-selector indicators
  float wjv[6], mjw[6];
  #pragma unroll
  for (int jf = 0; jf < 6; ++jf) {
    float e2 = (float)(1 << jf) * 0.125f;                  // 2^(jf-3), exact
    float tt = fminf(fmaxf(aM - (float)jf, 0.0f), 1.0f);
    float wj = (1.0f - __builtin_amdgcn_cosf(tt * 0.49974652f)) * 0.5f;
    wjv[jf] = wj;
    mjw[jf] = (e2 * 3.14f) * wj;                           // mj*wj, same assoc
  }
  const float f_d0 = (d == 0) ? 1.0f : 0.0f;
  const float fea[3] = { (d == 1) ? 1.0f : 0.0f,
                         (d == 2) ? 1.0f : 0.0f,
                         (d == 3) ? 1.0f : 0.0f };

  short8 pg[8];
  posenc_pack(X, h, wjv, mjw, f_d0, fea, pg);
  __syncthreads();   // slot0 (layer-0 lower half) landed

  mlp_layer<3, true , true >(pg, s0s, s1s, sWl[0], sWl[1], aoff, wsW + 0*256, bind, wsW + 0*16384, wsW + 1*16384, tid, c32);
  mlp_layer<8, false, true >(pg, s0s, s1s, sWl[0], sWl[1], aoff, wsW + 1*256, bind, wsW + 1*16384, wsW + 2*16384, tid, c32);
  mlp_layer<8, false, true >(pg, s0s, s1s, sWl[0], sWl[1], aoff, wsW + 2*256, bind, wsW + 2*16384, wsW + 3*16384, tid, c32);
  mlp_layer<8, false, true >(pg, s0s, s1s, sWl[0], sWl[1], aoff, wsW + 3*256, bind, wsW + 3*16384, wsW + 4*16384, tid, c32);
  mlp_layer<8, false, true >(pg, s0s, s1s, sWl[0], sWl[1], aoff, wsW + 4*256, bind, wsW + 4*16384, wsW + 5*16384, tid, c32);
  mlp_layer<8, false, true >(pg, s0s, s1s, sWl[0], sWl[1], aoff, wsW + 5*256, bind, wsW + 5*16384, wsW + 6*16384, tid, c32);
  mlp_layer<8, false, false>(pg, s0s, s1s, sWl[0], sWl[1], aoff, wsW + 6*256, bind, wsW + 6*16384, wsW,           tid, c32);
  // (last layer's end barrier is unconditional -> s1 reads done before sH alias)

  // ---- heads: A = head weights from L2 ----
  {
    const unsigned short* hw = wsW + HOFF;
    short8 af0 = *(const short8*)(hw + c32 * 128 + 8 * h);
    f32x16 hacc = __builtin_amdgcn_mfma_f32_32x32x16_bf16(af0, pg[0], zf(), 0, 0, 0);
    #pragma unroll
    for (int ks = 1; ks < 8; ++ks) {
      short8 afrag = *(const short8*)(hw + c32 * 128 + ks * 16 + 8 * h);
      hacc = __builtin_amdgcn_mfma_f32_32x32x16_bf16(afrag, pg[ks], hacc, 0, 0, 0);
    }
    int rg = wv * 32 + c32;
    if (h == 0) {   // regs 0..3 = outs o=0..3
      *(float4*)(sH + rg * 8) = make_float4(hacc[0], hacc[1], hacc[2], hacc[3]);
    } else {        // regs 0..1 = outs o=4,5
      *(float2*)(sH + rg * 8 + 4) = make_float2(hacc[0], hacc[1]);
    }
  }
  __syncthreads();

  // ---- SE(3) epilogue, wave-parallel: lane = (sel, point) ----
  // sel 0..2: Jacobian column dd=sel of point pd; sel 3: warped output.
  if (lane < 32) {
    const int pd  = lane & 7;
    const int sel = lane >> 3;
    const int gpp = p0 + wv * 8 + pd;
    const int rb  = wv * 32 + pd * 4;    // value row; +1+dd = tangent rows
    float XX[3] = { x[gpp*3+0], x[gpp*3+1], x[gpp*3+2] };
    float w[3], v[3];
    #pragma unroll
    for (int i = 0; i < 3; ++i) {
      w[i] = sH[rb * 8 + i]     + bw[i];
      v[i] = sH[rb * 8 + 3 + i] + bv[i];
    }
    float th  = sqrtf(w[0]*w[0] + w[1]*w[1] + w[2]*w[2]);
    float ith = 1.0f / th;
    float u[3]  = { w[0]*ith, w[1]*ith, w[2]*ith };
    float vh[3] = { v[0]*ith, v[1]*ith, v[2]*ith };
    float s = sinf(th), c = cosf(th);
    float C2 = 1.0f - c;
    float ths = th - s;
    float uxx[3]; cross3(u, XX, uxx);
    float udx = dot3(u, XX);
    float uxv[3]; cross3(u, vh, uxv);
    float udv = dot3(u, vh);
    if (sel == 3) {
      #pragma unroll
      for (int i = 0; i < 3; ++i) {
        float Rx = XX[i] + s * uxx[i] + C2 * (u[i] * udx - XX[i]);
        float tt = th * vh[i] + C2 * uxv[i] + ths * (u[i] * udv - vh[i]);
        out[gpp*3 + i] = Rx + tt;
      }
    } else {
      const int dd = sel;
      float* Jout = out + (size_t)NPTS * 3 + (size_t)gpp * 9;
      float dwv[3], dvv[3];
      #pragma unroll
      for (int i = 0; i < 3; ++i) {
        dwv[i] = sH[(rb + 1 + dd) * 8 + i];
        dvv[i] = sH[(rb + 1 + dd) * 8 + 3 + i];
      }
      float dth = dot3(w, dwv) * ith;
      float du[3], dvhv[3];
      #pragma unroll
      for (int i = 0; i < 3; ++i) {
        du[i]   = (dwv[i] - u[i]  * dth) * ith;
        dvhv[i] = (dvv[i] - vh[i] * dth) * ith;
      }
      float ex[3] = { dd == 0 ? 1.0f : 0.0f, dd == 1 ? 1.0f : 0.0f, dd == 2 ? 1.0f : 0.0f };
      float u_dd  = dd == 0 ? u[0] : (dd == 1 ? u[1] : u[2]);
      float dsv  = c  * dth;
      float dC2  = s  * dth;
      float dths = C2 * dth;
      float duxx[3]; cross3(du, XX, duxx);
      float uxe[3];  cross3(u, ex, uxe);
      float dudx = dot3(du, XX) + u_dd;
      float duxv[3]; cross3(du, vh, duxv);
      float uxdv[3]; cross3(u, dvhv, uxdv);
      float dudv = dot3(du, vh) + dot3(u, dvhv);
      #pragma unroll
      for (int i = 0; i < 3; ++i) {
        float dRx = ex[i] + dsv * uxx[i] + s * (duxx[i] + uxe[i])
                  + dC2 * (u[i] * udx - XX[i])
                  + C2 * (du[i] * udx + u[i] * dudx - ex[i]);
        float dt  = dth * vh[i] + th * dvhv[i] + dC2 * uxv[i]
                  + C2 * (duxv[i] + uxdv[i])
                  + dths * (u[i] * udv - vh[i])
                  + ths * (du[i] * udv + u[i] * dudv - dvhv[i]);
        Jout[i * 3 + dd] = dRx + dt;
      }
    }
  }
}

extern "C" void kernel_launch(void* const* d_in, const int* in_sizes, int n_in,
                              void* d_out, int out_size, void* d_ws, size_t ws_size,
                              hipStream_t stream) {
  const float* x    = (const float*)d_in[0];
  const float* W_in = (const float*)d_in[1];
  const float* b_in = (const float*)d_in[2];
  const float* Ws   = (const float*)d_in[3];
  const float* bs   = (const float*)d_in[4];
  const float* Ww   = (const float*)d_in[5];
  const float* bw   = (const float*)d_in[6];
  const float* Wv   = (const float*)d_in[7];
  const float* bv   = (const float*)d_in[8];
  const int*   itp  = (const int*)d_in[9];
  unsigned short* wsW = (unsigned short*)d_ws;   // (7*16384 + 4096) bf16

  convert_weights<<<dim3((HOFF + HSZ + 255) / 256), dim3(256), 0, stream>>>(
      W_in, b_in, Ws, bs, Ww, Wv, wsW);
  nerfies_mfma<<<dim3(NBLK), dim3(THREADS), 0, stream>>>(
      x, bw, bv, wsW, itp, (float*)d_out);
}

// Round 12
// 179.915 us; speedup vs baseline: 1.0869x; 1.0869x over previous
//
#include <hip/hip_runtime.h>
#include <math.h>

#define NPTS    131072
#define PPB     64            // points per block (4 waves x 16 points, 2 B-tiles/wave)
#define THREADS 256
#define NBLK    (NPTS / PPB)  // 2048
#define HOFF    (7 * 16384)   // head-weight offset in wsW (bf16 elems)
#define HSZ     (32 * 128)    // head block: 32 rows (6 used), 128 k

typedef __attribute__((ext_vector_type(8)))  short short8;
typedef __attribute__((ext_vector_type(16))) float f32x16;
typedef __attribute__((ext_vector_type(2)))  short s16x2;
typedef __attribute__((ext_vector_type(2)))  __bf16 bf16x2v;

union b8cv { short8 v; unsigned u[4]; };

__device__ __forceinline__ unsigned short f2bf(float f) {
  unsigned u = __float_as_uint(f);
  unsigned r = (u + 0x7fffu + ((u >> 16) & 1u)) >> 16;
  return (unsigned short)r;
}
// Native bf16 pack: gfx950 lowers fptrunc f32->bf16 to v_cvt_pk_bf16_f32
// (compiler-native casts get correct VALU->DPP hazard handling).
__device__ __forceinline__ unsigned pk2(float lo, float hi) {
  bf16x2v t;
  t[0] = (__bf16)lo;
  t[1] = (__bf16)hi;
  unsigned u; __builtin_memcpy(&u, &t, 4); return u;
}
__device__ __forceinline__ void gld16(const unsigned short* g, unsigned short* l) {
  __builtin_amdgcn_global_load_lds(
      (const __attribute__((address_space(1))) unsigned int*)(g),
      (__attribute__((address_space(3))) unsigned int*)(l), 16, 0, 0);
}
// rematerializable zero accumulator (not kept live across the kernel)
__device__ __forceinline__ f32x16 zf() {
  f32x16 z;
  #pragma unroll
  for (int e = 0; e < 16; ++e) z[e] = 0.0f;
  return z;
}
// broadcast the value-lane (lane & ~3) element of each 4-lane group: DPP quad_perm[0,0,0,0]
__device__ __forceinline__ float qbcast0(float v) {
  return __int_as_float(
      __builtin_amdgcn_mov_dpp(__float_as_int(v), 0x000, 0xf, 0xf, true));
}
// packed-bf16 ReLU with quad value-lane masking
__device__ __forceinline__ unsigned relu_pk(unsigned p) {
  unsigned vs = (unsigned)__builtin_amdgcn_mov_dpp((int)p, 0x000, 0xf, 0xf, true);
  s16x2 m2; __builtin_memcpy(&m2, &vs, 4);
  m2 = m2 >> 15;                          // 0xFFFF per negative half
  unsigned m; __builtin_memcpy(&m, &m2, 4);
  unsigned r;
  asm("v_bfi_b32 %0, %1, 0, %2" : "=v"(r) : "v"(m), "v"(p));
  return r;
}
__device__ __forceinline__ void cross3(const float a[3], const float b[3], float o[3]) {
  o[0] = a[1]*b[2] - a[2]*b[1];
  o[1] = a[2]*b[0] - a[0]*b[2];
  o[2] = a[0]*b[1] - a[1]*b[0];
}
__device__ __forceinline__ float dot3(const float a[3], const float b[3]) {
  return a[0]*b[0] + a[1]*b[1] + a[2]*b[2];
}

// ---- weights -> bf16 workspace: 7x[128c][128k] identity + heads 32x128 ----
// Biases stuffed into layer-0's dead k>=64 space (see r3 derivation):
//   flat j = l*128 + mt*32 + rD -> wsW elem (j>>6)*128 + 64 + (j&63).
__global__ void convert_weights(const float* __restrict__ W_in,
                                const float* __restrict__ b_in,
                                const float* __restrict__ Ws,
                                const float* __restrict__ bs,
                                const float* __restrict__ Ww,
                                const float* __restrict__ Wv,
                                unsigned short* __restrict__ wsW) {
  int idx = blockIdx.x * 256 + threadIdx.x;
  if (idx >= HOFF + HSZ) return;
  float v;
  if (idx < HOFF) {
    int l = idx >> 14, r = idx & 16383, c = r >> 7, k = r & 127;
    if (l == 0) {
      if (k < 39) {
        v = W_in[c * 39 + k];
      } else if (k >= 64 && c < 14) {
        int j  = c * 64 + (k - 64);          // 0..895
        int lb = j >> 7, rr = j & 127;
        int mt = rr >> 5, rd = rr & 31;
        int e2 = rd & 3, hh = (rd >> 2) & 1, q = rd >> 3;
        int src = 32*mt + 16*(q>>1) + 8*hh + 4*(q&1) + e2;
        v = (lb == 0) ? b_in[src] : bs[(lb - 1) * 128 + src];
      } else {
        v = 0.0f;
      }
    } else {
      v = Ws[(l - 1) * 16384 + c * 128 + k];
    }
  } else {
    int r = idx - HOFF, o = r >> 7, k = r & 127;
    v = (o < 3) ? Ww[o * 128 + k] : (o < 6) ? Wv[(o - 3) * 128 + k] : 0.0f;
  }
  wsW[idx] = f2bf(v);
}

// DMA a FULL layer (128 rows, 32 KB) into an LDS slot, XOR-chunk-swizzled:
// slot row R, chunk-pos chs holds global chunk chs^(R&15).
__device__ __forceinline__ void dma_full(const unsigned short* __restrict__ g,
                                         unsigned short* lds, int tid) {
  #pragma unroll
  for (int i = 0; i < 8; ++i) {
    int flat = i * 256 + tid;
    int R = flat >> 4, chs = flat & 15, ch = chs ^ (R & 15);
    gld16(g + R * 128 + ch * 8, lds + flat * 8);
  }
}

// bias-MFMA A-frag from a PRELOADED raw halfword (no VMEM load here --
// vmcnt retirement is in-order, so a load issued after dma_full would
// force draining the whole next-layer DMA at phase-1 start).
__device__ __forceinline__ short8 bias_from(unsigned raw) {
  b8cv cv;
  cv.u[0] = raw;
  cv.u[1] = 0; cv.u[2] = 0; cv.u[3] = 0;
  return cv.v;
}

// activation + pack two m-tiles' results: acc[2] (64 units) -> dst[0..3]
template <bool LEAKY>
__device__ __forceinline__ void act_pack(const f32x16 (&acc)[2], short8* dst) {
  #pragma unroll
  for (int mt = 0; mt < 2; ++mt)
    #pragma unroll
    for (int qh = 0; qh < 2; ++qh) {
      b8cv cv;
      #pragma unroll
      for (int qs = 0; qs < 2; ++qs) {
        int q = 2*qh + qs;
        if (LEAKY) {
          float pr[4];
          #pragma unroll
          for (int e2 = 0; e2 < 4; ++e2) {
            float post = acc[mt][4*q + e2];
            float vraw = qbcast0(post);
            pr[e2] = vraw > 0.0f ? post : post * 0.01f;
          }
          cv.u[2*qs]     = pk2(pr[0], pr[1]);
          cv.u[2*qs + 1] = pk2(pr[2], pr[3]);
        } else {
          cv.u[2*qs]     = relu_pk(pk2(acc[mt][4*q+0], acc[mt][4*q+1]));
          cv.u[2*qs + 1] = relu_pk(pk2(acc[mt][4*q+2], acc[mt][4*q+3]));
        }
      }
      dst[2*mt + qh] = cv.v;
    }
}

// One MLP layer, TWO B-tiles (16 points/wave), FULL-layer LDS staging.
// All per-layer VMEM loads (biases) are PRELOADED in the prologue, so no
// load is ever issued after this layer's dma_full -> phase-1's waitcnt
// leaves the 8 prefetch loads in flight (in-order vmcnt retirement), and
// the single end-of-layer barrier drains DMA issued a full layer earlier.
template <int NKS, bool LEAKY, bool HASNEXT>
__device__ __forceinline__ void mlp_layer(short8 (&pgA)[8], short8 (&pgB)[8],
                                          const unsigned short* scur,
                                          unsigned short* snxt,
                                          const int (&aoff)[8],
                                          const unsigned (&bfr)[4],
                                          const short8 bind,
                                          const unsigned short* __restrict__ Wnext,
                                          int tid, int c32) {
  if (HASNEXT) dma_full(Wnext, snxt, tid);   // lands by the end-of-layer barrier

  short8 tA[4], tB[4];                // phase-1 results (units 0-63)

  // ---- phase 1: output units 0-63 (m-tiles 0,1), rows sig+{0,32} ----
  {
    f32x16 aA[2], aB[2];
    __builtin_amdgcn_s_setprio(1);
    #pragma unroll
    for (int m = 0; m < 2; ++m) {
      f32x16 bias = __builtin_amdgcn_mfma_f32_32x32x16_bf16(
          bias_from(bfr[m]), bind, zf(), 0, 0, 0);
      short8 af0 = *(const short8*)(scur + m * 4096 + aoff[0]);
      aA[m] = __builtin_amdgcn_mfma_f32_32x32x16_bf16(af0, pgA[0], bias, 0, 0, 0);
      aB[m] = __builtin_amdgcn_mfma_f32_32x32x16_bf16(af0, pgB[0], bias, 0, 0, 0);
    }
    #pragma unroll
    for (int ks = 1; ks < NKS; ++ks) {
      #pragma unroll
      for (int m = 0; m < 2; ++m) {
        short8 af = *(const short8*)(scur + m * 4096 + aoff[ks]);
        aA[m] = __builtin_amdgcn_mfma_f32_32x32x16_bf16(af, pgA[ks], aA[m], 0, 0, 0);
        aB[m] = __builtin_amdgcn_mfma_f32_32x32x16_bf16(af, pgB[ks], aB[m], 0, 0, 0);
      }
    }
    __builtin_amdgcn_s_setprio(0);
    act_pack<LEAKY>(aA, tA);
    act_pack<LEAKY>(aB, tB);
  }

  // ---- phase 2: output units 64-127 (m-tiles 2,3), rows sig+{64,96} ----
  {
    f32x16 aA[2], aB[2];
    __builtin_amdgcn_s_setprio(1);
    #pragma unroll
    for (int m = 0; m < 2; ++m) {
      f32x16 bias = __builtin_amdgcn_mfma_f32_32x32x16_bf16(
          bias_from(bfr[2 + m]), bind, zf(), 0, 0, 0);
      short8 af0 = *(const short8*)(scur + (2 + m) * 4096 + aoff[0]);
      aA[m] = __builtin_amdgcn_mfma_f32_32x32x16_bf16(af0, pgA[0], bias, 0, 0, 0);
      aB[m] = __builtin_amdgcn_mfma_f32_32x32x16_bf16(af0, pgB[0], bias, 0, 0, 0);
    }
    #pragma unroll
    for (int ks = 1; ks < NKS; ++ks) {
      #pragma unroll
      for (int m = 0; m < 2; ++m) {
        short8 af = *(const short8*)(scur + (2 + m) * 4096 + aoff[ks]);
        aA[m] = __builtin_amdgcn_mfma_f32_32x32x16_bf16(af, pgA[ks], aA[m], 0, 0, 0);
        aB[m] = __builtin_amdgcn_mfma_f32_32x32x16_bf16(af, pgB[ks], aB[m], 0, 0, 0);
      }
    }
    __builtin_amdgcn_s_setprio(0);
    // all reads of old pg done -> write phase-2 results directly
    act_pack<LEAKY>(aA, &pgA[4]);
    act_pack<LEAKY>(aB, &pgB[4]);
  }

  #pragma unroll
  for (int i = 0; i < 4; ++i) { pgA[i] = tA[i]; pgB[i] = tB[i]; }

  if (HASNEXT) __syncthreads();   // scur reads done everywhere; snxt DMA landed
}

// ---- posenc with compile-time slot metadata (bit-identical formulas) ----
struct SK { int cls, a, t, jf; };   // cls: 0=zero, 1=pos(a=c), 2=enc
__device__ __forceinline__ constexpr SK slotk(int c) {
  return (c < 3)   ? SK{1, c, 0, 0}
       : (c >= 39) ? SK{0, 0, 0, 0}
       : SK{2, (c-3)/12, ((c-3)%12)/6, ((c-3)%12)%6};
}
__device__ __forceinline__ constexpr float e2sf(int jf) {   // e2 * 0.49974652f
  return (float)(1 << jf) * 0.125f * 0.49974652f;
}
__device__ __forceinline__ float eval_slot(SK k, const float (&X)[3],
                                           float sv, float cvv,
                                           const float (&wjv)[6],
                                           const float (&mjw)[6],
                                           float f_d0, const float (&fea)[3]) {
  if (k.cls == 0) return 0.0f;
  if (k.cls == 1) return X[k.a] * f_d0 + fea[k.a];
  float pv = (k.t ? cvv : sv) * wjv[k.jf];     // value row: (t==0?sin:cos)*wj
  float pt = (k.t ? -sv : cvv) * mjw[k.jf];    // tangent:  (t==0?cos:-sin)*mj*wj
  return pv * f_d0 + pt * fea[k.a];
}

__device__ __forceinline__ void posenc_pack(const float (&X)[3], int h,
                                            const float (&wjv)[6],
                                            const float (&mjw)[6],
                                            float f_d0, const float (&fea)[3],
                                            short8* pg) {
  const bool hI = (h != 0);
  #pragma unroll
  for (int j = 4; j < 8; ++j) pg[j] = (short8)0;
  #pragma unroll
  for (int j = 0; j < 4; ++j) {
    b8cv cv;
    #pragma unroll
    for (int ii = 0; ii < 4; ++ii) {
      int i = 4*j + ii;
      int mt = i >> 3, rr = i & 7, q = rr >> 1, s = rr & 1;
      int u0 = 32*mt + 16*(q>>1) + 4*(q&1) + 2*s;    // h-part handled below
      float vp[2];
      #pragma unroll
      for (int ci = 0; ci < 2; ++ci) {
        const SK k0 = slotk(u0 + ci);          // h = 0 variant
        const SK k1 = slotk(u0 + ci + 8);      // h = 1 variant
        float rev0 = (k0.cls == 2) ? X[k0.a] * e2sf(k0.jf) : 0.0f;
        float rev1 = (k1.cls == 2) ? X[k1.a] * e2sf(k1.jf) : 0.0f;
        float rev  = hI ? rev1 : rev0;
        float fr   = rev - floorf(rev);
        float sv   = __builtin_amdgcn_sinf(fr);
        float cvv  = __builtin_amdgcn_cosf(fr);
        float v0 = eval_slot(k0, X, sv, cvv, wjv, mjw, f_d0, fea);
        float v1 = eval_slot(k1, X, sv, cvv, wjv, mjw, f_d0, fea);
        vp[ci] = hI ? v1 : v0;
      }
      cv.u[ii] = pk2(vp[0], vp[1]);
    }
    pg[j] = cv.v;
  }
}

__global__ __launch_bounds__(THREADS, 2)
void nerfies_mfma(const float* __restrict__ x,
                  const float* __restrict__ bw,
                  const float* __restrict__ bv,
                  const unsigned short* __restrict__ wsW,
                  const int* __restrict__ iterp,
                  float* __restrict__ out)
{
  __shared__ __align__(16) unsigned short sWl[2][128 * 128];  // 2x32 KB full slots
  float* sH = (float*)sWl[1];                                 // heads alias slot 1

  const int tid  = threadIdx.x;
  const int lane = tid & 63;
  const int wv   = tid >> 6;
  const int c32  = lane & 31;
  const int h    = lane >> 5;
  const int p0   = blockIdx.x * PPB;
  // sigma: swap bits 2<->3 (A-row permutation making next-layer B = identity)
  const int sig  = (c32 & 0x13) | ((c32 & 4) << 1) | ((c32 & 8) >> 1);

  // lane's act row: point-group A = wv*16 + (c32>>2), group B = +8, tangent d
  const int d   = c32 & 3;
  const int gpA = p0 + wv * 16 + (c32 >> 2);
  const int gpB = gpA + 8;

  // ===== ALL VMEM loads BEFORE the prologue DMA (in-order vmcnt: any load
  // issued after the 8 global_load_lds would drain them when waited on) ====
  float XA[3] = { x[gpA * 3 + 0], x[gpA * 3 + 1], x[gpA * 3 + 2] };
  float XB[3] = { x[gpB * 3 + 0], x[gpB * 3 + 1], x[gpB * 3 + 2] };
  int iraw = iterp[0];
  unsigned bfr[7][4];                 // 28 preloaded bias halfwords
  #pragma unroll
  for (int l = 0; l < 7; ++l) {
    const unsigned short* bb = wsW + l * 256;
    bfr[l][0] = bb[ 64 + c32];
    bfr[l][1] = bb[ 96 + c32];
    bfr[l][2] = bb[192 + c32];
    bfr[l][3] = bb[224 + c32];
  }

  // prologue: stage ALL of layer 0 into slot 0 (covered by posenc below)
  dma_full(wsW, sWl[0], tid);

  // per-lane A-frag addressing, invariant across ALL layers/phases:
  // elem offset within slot = sig*128 + m*4096 + aoff[ks], m = 0..3
  int aoff[8];
  #pragma unroll
  for (int ks = 0; ks < 8; ++ks) aoff[ks] = ((2*ks + h) ^ (sig & 15)) << 3;
  const unsigned short* s0s = sWl[0] + sig * 128;
  const unsigned short* s1s = sWl[1] + sig * 128;

  // bias-MFMA B-frag: 0.5 at k in {0,8} (elem0 of both halves), value cols only
  short8 bind;
  {
    b8cv cv;
    cv.u[0] = ((c32 & 3) == 0) ? 0x3F00u : 0u;
    cv.u[1] = 0; cv.u[2] = 0; cv.u[3] = 0;
    bind = cv.v;
  }

  float it = (iraw > 0 && iraw < 100000000) ? (float)iraw : ((const float*)iterp)[0];
  const float aM = 6.0f * it / 3000.0f;

  // hoisted posenc constants: anneal weights (6 jf) + row-selector indicators
  float wjv[6], mjw[6];
  #pragma unroll
  for (int jf = 0; jf < 6; ++jf) {
    float e2 = (float)(1 << jf) * 0.125f;                  // 2^(jf-3), exact
    float tt = fminf(fmaxf(aM - (float)jf, 0.0f), 1.0f);
    float wj = (1.0f - __builtin_amdgcn_cosf(tt * 0.49974652f)) * 0.5f;
    wjv[jf] = wj;
    mjw[jf] = (e2 * 3.14f) * wj;                           // mj*wj, same assoc
  }
  const float f_d0 = (d == 0) ? 1.0f : 0.0f;
  const float fea[3] = { (d == 1) ? 1.0f : 0.0f,
                         (d == 2) ? 1.0f : 0.0f,
                         (d == 3) ? 1.0f : 0.0f };

  short8 pgA[8], pgB[8];
  posenc_pack(XA, h, wjv, mjw, f_d0, fea, pgA);
  posenc_pack(XB, h, wjv, mjw, f_d0, fea, pgB);
  __syncthreads();   // slot0 (layer 0) fully landed

  mlp_layer<3, true , true >(pgA, pgB, s0s, sWl[1], aoff, bfr[0], bind, wsW + 1*16384, tid, c32);
  mlp_layer<8, false, true >(pgA, pgB, s1s, sWl[0], aoff, bfr[1], bind, wsW + 2*16384, tid, c32);
  mlp_layer<8, false, true >(pgA, pgB, s0s, sWl[1], aoff, bfr[2], bind, wsW + 3*16384, tid, c32);
  mlp_layer<8, false, true >(pgA, pgB, s1s, sWl[0], aoff, bfr[3], bind, wsW + 4*16384, tid, c32);
  mlp_layer<8, false, true >(pgA, pgB, s0s, sWl[1], aoff, bfr[4], bind, wsW + 5*16384, tid, c32);
  mlp_layer<8, false, true >(pgA, pgB, s1s, sWl[0], aoff, bfr[5], bind, wsW + 6*16384, tid, c32);
  mlp_layer<8, false, false>(pgA, pgB, s0s, sWl[1], aoff, bfr[6], bind, wsW,           tid, c32);
  // (layer 6 reads slot0; slot1 is free -> heads scratch)

  // ---- heads: A = head weights from L2 (shared by both B-tiles) ----
  {
    const unsigned short* hw = wsW + HOFF;
    short8 af0 = *(const short8*)(hw + c32 * 128 + 8 * h);
    f32x16 hA = __builtin_amdgcn_mfma_f32_32x32x16_bf16(af0, pgA[0], zf(), 0, 0, 0);
    f32x16 hB = __builtin_amdgcn_mfma_f32_32x32x16_bf16(af0, pgB[0], zf(), 0, 0, 0);
    #pragma unroll
    for (int ks = 1; ks < 8; ++ks) {
      short8 afrag = *(const short8*)(hw + c32 * 128 + ks * 16 + 8 * h);
      hA = __builtin_amdgcn_mfma_f32_32x32x16_bf16(afrag, pgA[ks], hA, 0, 0, 0);
      hB = __builtin_amdgcn_mfma_f32_32x32x16_bf16(afrag, pgB[ks], hB, 0, 0, 0);
    }
    int rgA = wv * 64 + c32;        // group A rows
    int rgB = rgA + 32;             // group B rows
    if (h == 0) {   // regs 0..3 = outs o=0..3
      *(float4*)(sH + rgA * 8) = make_float4(hA[0], hA[1], hA[2], hA[3]);
      *(float4*)(sH + rgB * 8) = make_float4(hB[0], hB[1], hB[2], hB[3]);
    } else {        // regs 0..1 = outs o=4,5
      *(float2*)(sH + rgA * 8 + 4) = make_float2(hA[0], hA[1]);
      *(float2*)(sH + rgB * 8 + 4) = make_float2(hB[0], hB[1]);
    }
  }
  __syncthreads();

  // ---- SE(3) epilogue, wave-parallel: lane = (sel, point) ----
  // sel 0..2: Jacobian column dd=sel of point pd; sel 3: warped output.
  {
    const int pd  = lane & 15;
    const int sel = lane >> 4;
    const int gpp = p0 + wv * 16 + pd;
    const int rb  = wv * 64 + (pd >> 3) * 32 + (pd & 7) * 4;
    float XX[3] = { x[gpp*3+0], x[gpp*3+1], x[gpp*3+2] };
    float w[3], v[3];
    #pragma unroll
    for (int i = 0; i < 3; ++i) {
      w[i] = sH[rb * 8 + i]     + bw[i];
      v[i] = sH[rb * 8 + 3 + i] + bv[i];
    }
    float th  = sqrtf(w[0]*w[0] + w[1]*w[1] + w[2]*w[2]);
    float ith = 1.0f / th;
    float u[3]  = { w[0]*ith, w[1]*ith, w[2]*ith };
    float vh[3] = { v[0]*ith, v[1]*ith, v[2]*ith };
    float s = sinf(th), c = cosf(th);
    float C2 = 1.0f - c;
    float ths = th - s;
    float uxx[3]; cross3(u, XX, uxx);
    float udx = dot3(u, XX);
    float uxv[3]; cross3(u, vh, uxv);
    float udv = dot3(u, vh);
    if (sel == 3) {
      #pragma unroll
      for (int i = 0; i < 3; ++i) {
        float Rx = XX[i] + s * uxx[i] + C2 * (u[i] * udx - XX[i]);
        float tt = th * vh[i] + C2 * uxv[i] + ths * (u[i] * udv - vh[i]);
        out[gpp*3 + i] = Rx + tt;
      }
    } else {
      const int dd = sel;
      float* Jout = out + (size_t)NPTS * 3 + (size_t)gpp * 9;
      float dwv[3], dvv[3];
      #pragma unroll
      for (int i = 0; i < 3; ++i) {
        dwv[i] = sH[(rb + 1 + dd) * 8 + i];
        dvv[i] = sH[(rb + 1 + dd) * 8 + 3 + i];
      }
      float dth = dot3(w, dwv) * ith;
      float du[3], dvhv[3];
      #pragma unroll
      for (int i = 0; i < 3; ++i) {
        du[i]   = (dwv[i] - u[i]  * dth) * ith;
        dvhv[i] = (dvv[i] - vh[i] * dth) * ith;
      }
      float ex[3] = { dd == 0 ? 1.0f : 0.0f, dd == 1 ? 1.0f : 0.0f, dd == 2 ? 1.0f : 0.0f };
      float u_dd  = dd == 0 ? u[0] : (dd == 1 ? u[1] : u[2]);
      float dsv  = c  * dth;
      float dC2  = s  * dth;
      float dths = C2 * dth;
      float duxx[3]; cross3(du, XX, duxx);
      float uxe[3];  cross3(u, ex, uxe);
      float dudx = dot3(du, XX) + u_dd;
      float duxv[3]; cross3(du, vh, duxv);
      float uxdv[3]; cross3(u, dvhv, uxdv);
      float dudv = dot3(du, vh) + dot3(u, dvhv);
      #pragma unroll
      for (int i = 0; i < 3; ++i) {
        float dRx = ex[i] + dsv * uxx[i] + s * (duxx[i] + uxe[i])
                  + dC2 * (u[i] * udx - XX[i])
                  + C2 * (du[i] * udx + u[i] * dudx - ex[i]);
        float dt  = dth * vh[i] + th * dvhv[i] + dC2 * uxv[i]
                  + C2 * (duxv[i] + uxdv[i])
                  + dths * (u[i] * udv - vh[i])
                  + ths * (du[i] * udv + u[i] * dudv - dvhv[i]);
        Jout[i * 3 + dd] = dRx + dt;
      }
    }
  }
}

extern "C" void kernel_launch(void* const* d_in, const int* in_sizes, int n_in,
                              void* d_out, int out_size, void* d_ws, size_t ws_size,
                              hipStream_t stream) {
  const float* x    = (const float*)d_in[0];
  const float* W_in = (const float*)d_in[1];
  const float* b_in = (const float*)d_in[2];
  const float* Ws   = (const float*)d_in[3];
  const float* bs   = (const float*)d_in[4];
  const float* Ww   = (const float*)d_in[5];
  const float* bw   = (const float*)d_in[6];
  const float* Wv   = (const float*)d_in[7];
  const float* bv   = (const float*)d_in[8];
  const int*   itp  = (const int*)d_in[9];
  unsigned short* wsW = (unsigned short*)d_ws;   // (7*16384 + 4096) bf16

  convert_weights<<<dim3((HOFF + HSZ + 255) / 256), dim3(256), 0, stream>>>(
      W_in, b_in, Ws, bs, Ww, Wv, wsW);
  nerfies_mfma<<<dim3(NBLK), dim3(THREADS), 0, stream>>>(
      x, bw, bv, wsW, itp, (float*)d_out);
}